// Round 1
// baseline (15567.593 us; speedup 1.0000x reference)
//
#include <hip/hip_runtime.h>
#include <math.h>

// Problem constants (fixed by setup_inputs)
constexpr int U    = 128;   // UNITS
constexpr int G4   = 512;   // 4*U gate width
constexpr int NCls = 10;    // classes
constexpr int TSTEPS = 1000;
constexpr int BATCH  = 256;

__device__ __forceinline__ float sigm(float x) {
    return 1.0f / (1.0f + __expf(-x));
}

// k = time_gate(t, tau, s); matches jnp.mod (floor-mod) semantics exactly:
// fmod is exact, then adjust sign.
__device__ __forceinline__ float tgate(float t, float tau, float s) {
    float r = fmodf(t - s, tau);
    if (r < 0.0f) r += tau;
    float phi = r / tau;
    float k;
    if (phi < 0.025f)      k = 40.0f * phi;          // 2*phi/R_ON
    else if (phi < 0.05f)  k = 2.0f - 40.0f * phi;   // 2 - 2*phi/R_ON
    else                   k = 0.001f * phi;         // ALPHA*phi
    return k;
}

// One workgroup per batch element; 512 threads = 8 waves; thread j owns gate
// column j of the 4U=512-wide z vectors. Whole T-loop inside the kernel:
// no grid sync, no inter-WG communication.
__global__ __launch_bounds__(512, 1) void plstm_fused(
    const float* __restrict__ inputs,  // [B,T,3]
    const float* __restrict__ times,   // [B,T]
    const float* __restrict__ Wx0,     // [3,512]
    const float* __restrict__ Wh0,     // [128,512]
    const float* __restrict__ b0,      // [512]
    const float* __restrict__ tau0,    // [128]
    const float* __restrict__ s0,      // [128]
    const float* __restrict__ Wx1,     // [128,512]
    const float* __restrict__ Wh1,     // [128,512]
    const float* __restrict__ b1,      // [512]
    const float* __restrict__ tau1,    // [128]
    const float* __restrict__ s1,      // [128]
    const float* __restrict__ gamma_,  // [128]
    const float* __restrict__ beta_,   // [128]
    const float* __restrict__ Wfc,     // [128,10]
    const float* __restrict__ bfc,     // [10]
    float* __restrict__ out)           // [B,T,10]
{
    const int b = blockIdx.x;
    const int j = threadIdx.x;  // 0..511

    __shared__ __align__(16) float h0s[U];
    __shared__ __align__(16) float h1s[U];
    __shared__ __align__(16) float hns[U];
    __shared__ __align__(16) float zs[G4];
    __shared__ float red[2];   // mu, rstd

    // Per-thread persistent parameters (loaded once)
    const float bj0  = b0[j];
    const float bj1  = b1[j];
    const float wx00 = Wx0[j];
    const float wx01 = Wx0[512 + j];
    const float wx02 = Wx0[1024 + j];

    float c0r = 0.0f, c1r = 0.0f;  // cell states live in unit-thread registers
    float tau0r = 0.f, s0r = 0.f, tau1r = 0.f, s1r = 0.f, gr = 0.f, br = 0.f;
    if (j < U) {
        tau0r = tau0[j]; s0r = s0[j];
        tau1r = tau1[j]; s1r = s1[j];
        gr = gamma_[j];  br = beta_[j];
        h0s[j] = 0.0f;   h1s[j] = 0.0f;
    }
    // Wave 0 keeps the FC weights in registers (each lane: units j and j+64)
    float wfc0[NCls], wfc1[NCls], bfcr[NCls];
    if (j < 64) {
        #pragma unroll
        for (int c = 0; c < NCls; ++c) {
            wfc0[c] = Wfc[j * NCls + c];
            wfc1[c] = Wfc[(j + 64) * NCls + c];
            bfcr[c] = bfc[c];
        }
    }
    __syncthreads();

    const float* xp = inputs + (size_t)b * TSTEPS * 3;
    const float* tp = times  + (size_t)b * TSTEPS;
    float*       op = out    + (size_t)b * TSTEPS * NCls;

    for (int t = 0; t < TSTEPS; ++t) {
        // x, t are wave-uniform loads (compiler scalarizes)
        const float x0 = xp[t * 3 + 0];
        const float x1 = xp[t * 3 + 1];
        const float x2 = xp[t * 3 + 2];
        const float tv = tp[t];

        // ---- layer 0: z0[j] = b0 + x@Wx0 + h0@Wh0 ----
        float acc = bj0 + x0 * wx00 + x1 * wx01 + x2 * wx02;
        #pragma unroll 4
        for (int u = 0; u < U; u += 4) {
            const float4 h4 = *reinterpret_cast<const float4*>(&h0s[u]);
            acc += h4.x * Wh0[(u + 0) * G4 + j];
            acc += h4.y * Wh0[(u + 1) * G4 + j];
            acc += h4.z * Wh0[(u + 2) * G4 + j];
            acc += h4.w * Wh0[(u + 3) * G4 + j];
        }
        zs[j] = acc;
        __syncthreads();

        // ---- layer 0 gates + state update (unit threads) ----
        if (j < U) {
            const float ig = sigm(zs[j]);
            const float fg = sigm(zs[j + U]);
            const float gg = tanhf(zs[j + 2 * U]);
            const float og = sigm(zs[j + 3 * U]);
            const float ch = fg * c0r + ig * gg;
            const float hh = og * tanhf(ch);
            const float k  = tgate(tv, tau0r, s0r);
            const float h0new = k * hh + (1.0f - k) * h0s[j];
            c0r    = k * ch + (1.0f - k) * c0r;
            h0s[j] = h0new;
        }
        __syncthreads();

        // ---- LayerNorm reduction (wave 0), two-pass variance ----
        if (j < 64) {
            const float a  = h0s[j];
            const float bv = h0s[j + 64];
            float ssum = a + bv;
            #pragma unroll
            for (int off = 1; off < 64; off <<= 1) ssum += __shfl_xor(ssum, off);
            const float mu = ssum * (1.0f / 128.0f);
            const float da = a - mu, db = bv - mu;
            float vsum = da * da + db * db;
            #pragma unroll
            for (int off = 1; off < 64; off <<= 1) vsum += __shfl_xor(vsum, off);
            const float var  = vsum * (1.0f / 128.0f);
            const float rstd = rsqrtf(var + 1e-3f);
            if (j == 0) { red[0] = mu; red[1] = rstd; }
        }
        __syncthreads();
        if (j < U) {
            hns[j] = gr * (h0s[j] - red[0]) * red[1] + br;
        }
        __syncthreads();

        // ---- layer 1: z1[j] = b1 + hn@Wx1 + h1@Wh1 ----
        float acc1 = bj1;
        #pragma unroll 4
        for (int u = 0; u < U; u += 4) {
            const float4 a4 = *reinterpret_cast<const float4*>(&hns[u]);
            const float4 b4 = *reinterpret_cast<const float4*>(&h1s[u]);
            acc1 += a4.x * Wx1[(u + 0) * G4 + j] + b4.x * Wh1[(u + 0) * G4 + j];
            acc1 += a4.y * Wx1[(u + 1) * G4 + j] + b4.y * Wh1[(u + 1) * G4 + j];
            acc1 += a4.z * Wx1[(u + 2) * G4 + j] + b4.z * Wh1[(u + 2) * G4 + j];
            acc1 += a4.w * Wx1[(u + 3) * G4 + j] + b4.w * Wh1[(u + 3) * G4 + j];
        }
        zs[j] = acc1;
        __syncthreads();

        // ---- layer 1 gates + state update ----
        if (j < U) {
            const float ig = sigm(zs[j]);
            const float fg = sigm(zs[j + U]);
            const float gg = tanhf(zs[j + 2 * U]);
            const float og = sigm(zs[j + 3 * U]);
            const float ch = fg * c1r + ig * gg;
            const float hh = og * tanhf(ch);
            const float k  = tgate(tv, tau1r, s1r);
            const float h1new = k * hh + (1.0f - k) * h1s[j];
            c1r    = k * ch + (1.0f - k) * c1r;
            h1s[j] = h1new;
        }
        __syncthreads();

        // ---- FC + softmax (wave 0) ----
        if (j < 64) {
            const float a  = h1s[j];
            const float bv = h1s[j + 64];
            float p[NCls];
            #pragma unroll
            for (int c = 0; c < NCls; ++c)
                p[c] = a * wfc0[c] + bv * wfc1[c];
            #pragma unroll
            for (int off = 1; off < 64; off <<= 1) {
                #pragma unroll
                for (int c = 0; c < NCls; ++c) p[c] += __shfl_xor(p[c], off);
            }
            float m = -1e30f;
            #pragma unroll
            for (int c = 0; c < NCls; ++c) { p[c] += bfcr[c]; m = fmaxf(m, p[c]); }
            float ssum = 0.0f;
            #pragma unroll
            for (int c = 0; c < NCls; ++c) { p[c] = __expf(p[c] - m); ssum += p[c]; }
            const float inv = 1.0f / ssum;
            if (j < NCls) op[t * NCls + j] = p[j] * inv;
        }
        // No extra sync needed: next write hazard (zs) is already fenced by the
        // sync after the layer-1 gate read above.
    }
}

extern "C" void kernel_launch(void* const* d_in, const int* in_sizes, int n_in,
                              void* d_out, int out_size, void* d_ws, size_t ws_size,
                              hipStream_t stream) {
    const float* inputs = (const float*)d_in[0];
    const float* times  = (const float*)d_in[1];
    const float* Wx0    = (const float*)d_in[2];
    const float* Wh0    = (const float*)d_in[3];
    const float* b0     = (const float*)d_in[4];
    const float* tau0   = (const float*)d_in[5];
    const float* s0     = (const float*)d_in[6];
    const float* Wx1    = (const float*)d_in[7];
    const float* Wh1    = (const float*)d_in[8];
    const float* b1     = (const float*)d_in[9];
    const float* tau1   = (const float*)d_in[10];
    const float* s1     = (const float*)d_in[11];
    const float* gamma_ = (const float*)d_in[12];
    const float* beta_  = (const float*)d_in[13];
    const float* Wfc    = (const float*)d_in[14];
    const float* bfc    = (const float*)d_in[15];
    float* out = (float*)d_out;

    dim3 grid(BATCH);
    dim3 block(512);
    hipLaunchKernelGGL(plstm_fused, grid, block, 0, stream,
                       inputs, times, Wx0, Wh0, b0, tau0, s0,
                       Wx1, Wh1, b1, tau1, s1, gamma_, beta_, Wfc, bfc, out);
}